// Round 1
// baseline (773.807 us; speedup 1.0000x reference)
//
#include <hip/hip_runtime.h>
#include <math.h>

// ---------------- workspace layout (floats) ----------------
#define WS_W12   0                         // [9][9][32]      = 2592
#define WS_B12   2592                      // 32
#define WS_W34   2624                      // [32][9][9][64]  = 165888
#define WS_B34   (2624 + 165888)           // 64
#define WS_P1    (WS_B34 + 64)             // [64][32][30][30] = 1843200
#define WS_EMB   (WS_P1 + 64*32*30*30)     // [64][1600]       = 102400
#define WS_LOG   (WS_EMB + 64*1600)        // [64][3]

// ---------------- kernel A1: compose conv1*conv2 -> 9x9, 1->32ch ----------
__global__ __launch_bounds__(256) void k_prep12(
    const float* __restrict__ w1, const float* __restrict__ b1,
    const float* __restrict__ w2, const float* __restrict__ b2,
    float* __restrict__ W12, float* __restrict__ B12)
{
    int t = blockIdx.x * 256 + threadIdx.x;   // 0..2591
    if (t < 2592) {
        int oc = t & 31;
        int uv = t >> 5;        // 0..80
        int u = uv / 9, v = uv % 9;
        int ey0 = max(0, u - 4), ey1 = min(4, u);
        int ex0 = max(0, v - 4), ex1 = min(4, v);
        float s = 0.f;
        for (int mc = 0; mc < 32; ++mc) {
            for (int ey = ey0; ey <= ey1; ++ey)
                for (int ex = ex0; ex <= ex1; ++ex)
                    s += w2[((oc * 32 + mc) * 5 + ey) * 5 + ex] *
                         w1[(mc * 5 + (u - ey)) * 5 + (v - ex)];
        }
        W12[(u * 9 + v) * 32 + oc] = s;   // [u][v][oc]
    }
    if (t < 32) {
        float s = b2[t];
        for (int mc = 0; mc < 32; ++mc) {
            float ws = 0.f;
            for (int e = 0; e < 25; ++e) ws += w2[(t * 32 + mc) * 25 + e];
            s += b1[mc] * ws;
        }
        B12[t] = s;
    }
}

// ---------------- kernel A2: compose conv3*conv4 -> 9x9, 32->64ch ---------
__global__ __launch_bounds__(256) void k_prep34(
    const float* __restrict__ w3, const float* __restrict__ b3,
    const float* __restrict__ w4, const float* __restrict__ b4,
    float* __restrict__ W34, float* __restrict__ B34)
{
    int t = blockIdx.x * 256 + threadIdx.x;   // 0..165887
    if (t < 64 * 32 * 81) {
        int oc = t & 63;
        int r  = t >> 6;          // ic*81 + uv
        int ic = r / 81;
        int uv = r % 81;
        int u = uv / 9, v = uv % 9;
        int ey0 = max(0, u - 4), ey1 = min(4, u);
        int ex0 = max(0, v - 4), ex1 = min(4, v);
        float s = 0.f;
        for (int mc = 0; mc < 64; ++mc) {
            for (int ey = ey0; ey <= ey1; ++ey)
                for (int ex = ex0; ex <= ex1; ++ex)
                    s += w4[((oc * 64 + mc) * 5 + ey) * 5 + ex] *
                         w3[((mc * 32 + ic) * 5 + (u - ey)) * 5 + (v - ex)];
        }
        W34[((ic * 9 + u) * 9 + v) * 64 + oc] = s;   // [ic][u][v][oc]
    }
    if (t < 64) {
        float s = b4[t];
        for (int mc = 0; mc < 64; ++mc) {
            float ws = 0.f;
            for (int e = 0; e < 25; ++e) ws += w4[(t * 64 + mc) * 25 + e];
            s += b3[mc] * ws;
        }
        B34[t] = s;
    }
}

// ---------------- kernel B: fused 9x9 conv12 + 4x4 maxpool ----------------
// grid = 64 batches * 30 pool-rows; block = 256 = 32 oc * 8 px-groups
__global__ __launch_bounds__(256) void k_conv12(
    const float* __restrict__ x, const float* __restrict__ W12,
    const float* __restrict__ B12, float* __restrict__ P1)
{
    __shared__ float sIn[12][128];     // input rows 4py..4py+11
    __shared__ float sW[81 * 32];      // [ky*9+kx][oc]

    int b  = blockIdx.x / 30;
    int py = blockIdx.x % 30;
    int t  = threadIdx.x;

    const float* xb = x + b * 128 * 128;
    for (int i = t; i < 12 * 32; i += 256) {          // 384 float4
        int row = i >> 5, c4 = i & 31;
        ((float4*)sIn[row])[c4] =
            ((const float4*)(xb + (4 * py + row) * 128))[c4];
    }
    for (int i = t; i < 648; i += 256)                // 2592 floats
        ((float4*)sW)[i] = ((const float4*)W12)[i];
    __syncthreads();

    int oc = t & 31;
    int pg = t >> 5;                                  // 0..7
    float bias = B12[oc];

    for (int j = 0; j < 4; ++j) {
        int px = pg + 8 * j;
        if (px >= 30) break;
        float acc[4][4];
        #pragma unroll
        for (int iy = 0; iy < 4; ++iy)
            #pragma unroll
            for (int ix = 0; ix < 4; ++ix) acc[iy][ix] = 0.f;

        for (int ky = 0; ky < 9; ++ky) {
            float w[9];
            #pragma unroll
            for (int kx = 0; kx < 9; ++kx) w[kx] = sW[(ky * 9 + kx) * 32 + oc];
            #pragma unroll
            for (int iy = 0; iy < 4; ++iy) {
                const float* rp = sIn[iy + ky] + 4 * px;
                float4 A = ((const float4*)rp)[0];
                float4 Bq = ((const float4*)rp)[1];
                float4 Cq = ((const float4*)rp)[2];
                float win[12] = {A.x, A.y, A.z, A.w, Bq.x, Bq.y, Bq.z, Bq.w,
                                 Cq.x, Cq.y, Cq.z, Cq.w};
                #pragma unroll
                for (int ix = 0; ix < 4; ++ix)
                    #pragma unroll
                    for (int kx = 0; kx < 9; ++kx)
                        acc[iy][ix] = fmaf(w[kx], win[ix + kx], acc[iy][ix]);
            }
        }
        float m = -INFINITY;
        #pragma unroll
        for (int iy = 0; iy < 4; ++iy)
            #pragma unroll
            for (int ix = 0; ix < 4; ++ix) m = fmaxf(m, acc[iy][ix]);
        P1[((b * 32 + oc) * 30 + py) * 30 + px] = m + bias;
    }
}

// ---------------- kernel C: fused 9x9 conv34 + 4x4 maxpool ----------------
// grid = 64 batches * 5 pool-rows; block = 640 = 64 oc * (2 iy-halves * 5 px)
__global__ __launch_bounds__(640) void k_conv34(
    const float* __restrict__ P1, const float* __restrict__ W34,
    const float* __restrict__ B34, float* __restrict__ emb)
{
    __shared__ float sIn[32][12][32];   // [ic][row 4py..4py+11][col, pad 30->32]
    __shared__ float sPool[10][64];

    int b  = blockIdx.x / 5;
    int py = blockIdx.x % 5;
    int t  = threadIdx.x;

    for (int i = t; i < 32 * 12 * 30; i += 640) {
        int ic  = i / 360;
        int rr  = i % 360;
        int row = rr / 30, col = rr % 30;
        sIn[ic][row][col] =
            P1[((b * 32 + ic) * 30 + (4 * py + row)) * 30 + col];
    }
    __syncthreads();

    int oc   = t & 63;
    int grp  = t >> 6;          // 0..9
    int iyh  = grp / 5;         // 0..1  -> iy in {2iyh, 2iyh+1}
    int cgrp = grp % 5;         // 0..4  -> c in 4cgrp..4cgrp+3 (== pool col)

    float acc[2][4];
    #pragma unroll
    for (int d = 0; d < 2; ++d)
        #pragma unroll
        for (int ix = 0; ix < 4; ++ix) acc[d][ix] = 0.f;

    for (int ic = 0; ic < 32; ++ic) {
        for (int ky = 0; ky < 9; ++ky) {
            float w[9];
            #pragma unroll
            for (int kx = 0; kx < 9; ++kx)
                w[kx] = W34[((ic * 9 + ky) * 9 + kx) * 64 + oc];
            #pragma unroll
            for (int d = 0; d < 2; ++d) {
                int row = 2 * iyh + d + ky;
                const float* rp = &sIn[ic][row][4 * cgrp];
                float4 A = ((const float4*)rp)[0];
                float4 Bq = ((const float4*)rp)[1];
                float4 Cq = ((const float4*)rp)[2];
                float win[12] = {A.x, A.y, A.z, A.w, Bq.x, Bq.y, Bq.z, Bq.w,
                                 Cq.x, Cq.y, Cq.z, Cq.w};
                #pragma unroll
                for (int ix = 0; ix < 4; ++ix)
                    #pragma unroll
                    for (int kx = 0; kx < 9; ++kx)
                        acc[d][ix] = fmaf(w[kx], win[ix + kx], acc[d][ix]);
            }
        }
    }

    float pmax = -INFINITY;
    #pragma unroll
    for (int d = 0; d < 2; ++d)
        #pragma unroll
        for (int ix = 0; ix < 4; ++ix) pmax = fmaxf(pmax, acc[d][ix]);
    sPool[grp][oc] = pmax;
    __syncthreads();

    if (grp < 5) {
        float m = fmaxf(sPool[grp][oc], sPool[grp + 5][oc]) + B34[oc];
        // emb layout: [b][oc*25 + py*5 + px]
        emb[b * 1600 + oc * 25 + py * 5 + grp] = m;
    }
}

// ---------------- kernel D: FC heads (only needed output columns) ---------
__device__ __forceinline__ float block_sum256(float v, float* sred, int t) {
    #pragma unroll
    for (int o = 32; o; o >>= 1) v += __shfl_down(v, o, 64);
    __syncthreads();
    if ((t & 63) == 0) sred[t >> 6] = v;
    __syncthreads();
    return sred[0] + sred[1] + sred[2] + sred[3];
}

// grid = 128: blockIdx>>6 = head (0:edge,1:endpoint), blockIdx&63 = batch
__global__ __launch_bounds__(256) void k_fc(
    const float* __restrict__ emb,
    const float* __restrict__ w_ed1, const float* __restrict__ b_ed1,
    const float* __restrict__ w_ed2, const float* __restrict__ b_ed2,
    const float* __restrict__ w_ep1, const float* __restrict__ b_ep1,
    const float* __restrict__ w_ep2, const float* __restrict__ b_ep2,
    const int* __restrict__ esrc, const int* __restrict__ edst,
    float* __restrict__ logits)
{
    __shared__ float se[1600];
    __shared__ float sred[4];

    int head = blockIdx.x >> 6;
    int b    = blockIdx.x & 63;
    int j    = threadIdx.x;     // 0..255 = hidden unit

    const float* W1 = head ? w_ep1 : w_ed1;
    const float* B1 = head ? b_ep1 : b_ed1;

    for (int i = j; i < 1600; i += 256) se[i] = emb[b * 1600 + i];
    __syncthreads();

    float s = B1[j];
    for (int k = 0; k < 1600; ++k) s = fmaf(se[k], W1[k * 256 + j], s);
    float h = fmaxf(s, 0.f);

    if (head == 0) {
        // E logit, column 0 (first path symbol = adjacency[0])
        float p = h * w_ed2[j * 120 + 0];
        float tot = block_sum256(p, sred, j);
        if (j == 0) logits[b * 3 + 0] = tot + b_ed2[0];
    } else {
        int c0 = esrc[0];
        int c1 = edst[0];
        float p0 = h * w_ep2[j * 36 + c0];
        float p1 = h * w_ep2[j * 36 + c1];
        float t0 = block_sum256(p0, sred, j);
        float t1 = block_sum256(p1, sred, j);
        if (j == 0) {
            logits[b * 3 + 1] = t0 + b_ep2[c0];
            logits[b * 3 + 2] = t1 + b_ep2[c1];
        }
    }
}

// ---------------- kernel E: sigmoid products -> out ----------------------
__global__ __launch_bounds__(64) void k_final(
    const float* __restrict__ logits, float* __restrict__ out)
{
    int b = threadIdx.x;
    if (b < 64) {
        float e  = logits[b * 3 + 0];
        float p0 = logits[b * 3 + 1];
        float p1 = logits[b * 3 + 2];
        float se  = 1.f / (1.f + expf(-e));
        float sp0 = 1.f / (1.f + expf(-p0));
        float sp1 = 1.f / (1.f + expf(-p1));
        out[b] = se * sp0 * sp1;
    }
}

// ---------------- launch --------------------------------------------------
extern "C" void kernel_launch(void* const* d_in, const int* in_sizes, int n_in,
                              void* d_out, int out_size, void* d_ws, size_t ws_size,
                              hipStream_t stream)
{
    const float* x     = (const float*)d_in[0];
    const float* w1    = (const float*)d_in[1];
    const float* b1    = (const float*)d_in[2];
    const float* w2    = (const float*)d_in[3];
    const float* b2    = (const float*)d_in[4];
    const float* w3    = (const float*)d_in[5];
    const float* b3    = (const float*)d_in[6];
    const float* w4    = (const float*)d_in[7];
    const float* b4    = (const float*)d_in[8];
    const float* w_ed1 = (const float*)d_in[9];
    const float* b_ed1 = (const float*)d_in[10];
    const float* w_ed2 = (const float*)d_in[11];
    const float* b_ed2 = (const float*)d_in[12];
    const float* w_ep1 = (const float*)d_in[13];
    const float* b_ep1 = (const float*)d_in[14];
    const float* w_ep2 = (const float*)d_in[15];
    const float* b_ep2 = (const float*)d_in[16];
    const int*   esrc  = (const int*)d_in[17];
    const int*   edst  = (const int*)d_in[18];

    float* ws  = (float*)d_ws;
    float* out = (float*)d_out;

    k_prep12<<<11, 256, 0, stream>>>(w1, b1, w2, b2, ws + WS_W12, ws + WS_B12);
    k_prep34<<<648, 256, 0, stream>>>(w3, b3, w4, b4, ws + WS_W34, ws + WS_B34);
    k_conv12<<<64 * 30, 256, 0, stream>>>(x, ws + WS_W12, ws + WS_B12, ws + WS_P1);
    k_conv34<<<64 * 5, 640, 0, stream>>>(ws + WS_P1, ws + WS_W34, ws + WS_B34,
                                         ws + WS_EMB);
    k_fc<<<128, 256, 0, stream>>>(ws + WS_EMB, w_ed1, b_ed1, w_ed2, b_ed2,
                                  w_ep1, b_ep1, w_ep2, b_ep2, esrc, edst,
                                  ws + WS_LOG);
    k_final<<<1, 64, 0, stream>>>(ws + WS_LOG, out);
}